// Round 14
// baseline (196.511 us; speedup 1.0000x reference)
//
#include <hip/hip_runtime.h>
#include <hip/hip_bf16.h>

typedef __attribute__((ext_vector_type(8))) short short8;
typedef __attribute__((ext_vector_type(4))) float f32x4;

#define DDIM 256
#define NROWS 131072
#define GBLK 256              // persistent: 1 block per CU
#define RPB (NROWS / GBLK)    // 512 rows per block = 2 generations of 256
#define NSTEP 16              // 2 generations x 8 kk-steps

static __device__ __forceinline__ unsigned short f2bf(float f){
  unsigned b = __builtin_bit_cast(unsigned, f);
  b += 0x7FFFu + ((b >> 16) & 1u);          // RNE round to bf16
  return (unsigned short)(b >> 16);
}

// Wave64 sum-reduction via DPP (VALU-only). row_shr 1/2/4/8 +
// row_bcast:15/31 -> total in lane 63; readlane broadcasts.
static __device__ __forceinline__ float wave_sum_bcast(float x){
  int v = __builtin_bit_cast(int, x);
#define DPP_ADD(ctrl)                                                          \
  v = __builtin_bit_cast(int,                                                  \
        __builtin_bit_cast(float, v) +                                         \
        __builtin_bit_cast(float,                                              \
          __builtin_amdgcn_update_dpp(0, v, (ctrl), 0xF, 0xF, true)))
  DPP_ADD(0x111); DPP_ADD(0x112); DPP_ADD(0x114); DPP_ADD(0x118);
  DPP_ADD(0x142); DPP_ADD(0x143);
#undef DPP_ADD
  return __builtin_bit_cast(float, __builtin_amdgcn_readlane(v, 63));
}

// ---------------------------------------------------------------------------
// Kernel A (unchanged, verified r9-r11): Q columns via 256 Householder steps;
// 2 cols/wave, depth-4 rotating U-row prefetch, v.v inline via 3rd DPP chain.
// ---------------------------------------------------------------------------
__global__ __launch_bounds__(256) void compute_q(const float* __restrict__ U,
                                                 unsigned short* __restrict__ Qt){
  const int lane = threadIdx.x & 63;
  const int wv   = threadIdx.x >> 6;
  const int pair = blockIdx.x * 4 + wv;
  const int j0 = pair * 2, j1 = j0 + 1;

  float u0[4], u1[4], r0[4], r1[4], r2[4], r3[4];
#pragma unroll
  for (int e = 0; e < 4; ++e){
    const int i = e * 64 + lane;
    u0[e] = (i == j0) ? 1.f : 0.f;
    u1[e] = (i == j1) ? 1.f : 0.f;
    r0[e] = U[0 * 256 + i];
    r1[e] = U[1 * 256 + i];
    r2[e] = U[2 * 256 + i];
    r3[e] = U[3 * 256 + i];
  }

#define QSTEP(R, KN)                                                           \
  do {                                                                         \
    const float p0_ = (u0[0]*R[0] + u0[1]*R[1]) + (u0[2]*R[2] + u0[3]*R[3]);   \
    const float p1_ = (u1[0]*R[0] + u1[1]*R[1]) + (u1[2]*R[2] + u1[3]*R[3]);   \
    const float pv_ = (R[0]*R[0] + R[1]*R[1]) + (R[2]*R[2] + R[3]*R[3]);       \
    const float d0_ = wave_sum_bcast(p0_);                                     \
    const float d1_ = wave_sum_bcast(p1_);                                     \
    const float dv_ = wave_sum_bcast(pv_);                                     \
    const float inv_ = 2.0f * __builtin_amdgcn_rcpf(dv_);                      \
    const float c0_ = d0_ * inv_, c1_ = d1_ * inv_;                            \
    _Pragma("unroll")                                                          \
    for (int e = 0; e < 4; ++e){                                               \
      u0[e] = fmaf(-c0_, R[e], u0[e]);                                         \
      u1[e] = fmaf(-c1_, R[e], u1[e]);                                         \
      R[e] = U[(size_t)(KN) * 256 + e * 64 + lane];                            \
    }                                                                          \
  } while (0)

  for (int k = 0; k < 256; k += 4){
    const int k4 = (k+4) & 255, k5 = (k+5) & 255, k6 = (k+6) & 255, k7 = (k+7) & 255;
    QSTEP(r0, k4); QSTEP(r1, k5); QSTEP(r2, k6); QSTEP(r3, k7);
  }
#undef QSTEP

#pragma unroll
  for (int e = 0; e < 4; ++e){
    const int i = e * 64 + lane;
    Qt[(size_t)j0 * 256 + i] = f2bf(u0[e]);
    Qt[(size_t)j1 * 256 + i] = f2bf(u1[e]);
  }
}

// ---------------------------------------------------------------------------
// Kernel B: Y = X * Q, persistent full-N (r11 structure) with the spill fix:
// __launch_bounds__(1024, 4) grants the 128-VGPR budget (r11's missing 2nd
// arg let the allocator target 64 VGPRs -> ~120 MB scratch traffic in
// WRITE_SIZE and 148us).  Grid 256 = 1 block/CU; block owns 512 rows as 2
// generations of 256; full Qt (128 KB) staged once; ONE barrier total;
// depth-3 rotating X-slot ring prefetches across the generation boundary.
// Full-row XOR swizzle ((n&15)<<5): B-read slot = (kk*4+lg)^(lm<<1) -> 2
// lanes/16B slot = conflict-free (verified r5/r7/r11: SQ_LDS_BANK_CONFLICT=0).
// Steady regs: ring 24 + acc 64 (AGPR, unified) + addr ~20 ~= 110 <= 128.
// mfma_f32_16x16x32_bf16 layouts (m89/m97):
//   A: lane holds A[l&15][kk*32+8*(l>>4)+j]   B: same, n=l&15
//   D: D[(l>>4)*4+r][l&15]
// ---------------------------------------------------------------------------
__global__ __launch_bounds__(1024, 4) void gemm_xq(const float* __restrict__ X,
                                                   const unsigned short* __restrict__ Qt,
                                                   float* __restrict__ Y){
  __shared__ char qb[131072];                 // 256 rows (n) x 512 B (k, bf16)

  const int tid  = threadIdx.x;
  const int lane = tid & 63;
  const int wv   = tid >> 6;                  // 0..15
  const int lg   = lane >> 4;                 // 0..3
  const int lm   = lane & 15;
  const size_t rowbase = (size_t)blockIdx.x * RPB;

  // --- Qt stage loads (r5-verified pattern; issued first) ---
  f32x4 sv[8];
#pragma unroll
  for (int it = 0; it < 8; ++it){
    const int c = tid + it * 1024;            // 0..8191 chunks of 16B
    sv[it] = *reinterpret_cast<const f32x4*>(
        reinterpret_cast<const char*>(Qt) + ((size_t)c << 4));
  }

  // lane's X base: row = rowbase + gen*256 + wv*16 + lm, col = kk*32 + lg*8
  const float* xl = X + (rowbase + wv * 16 + lm) * DDIM + lg * 8;

  f32x4 f[3][2];                              // rotating ring (static idx)
#define LDX(slot, s)                                                           \
  do {                                                                         \
    const float* p_ = xl + (size_t)((s) >> 3) * (256 * DDIM) + ((s) & 7) * 32; \
    f[slot][0] = *reinterpret_cast<const f32x4*>(p_);                          \
    f[slot][1] = *reinterpret_cast<const f32x4*>(p_ + 4);                      \
  } while (0)

  // prologue: steps 0..2 in flight
  LDX(0, 0); LDX(1, 1); LDX(2, 2);

  // --- LDS writes (swizzled) + the single barrier of the kernel ---
#pragma unroll
  for (int it = 0; it < 8; ++it){
    const int c   = tid + it * 1024;
    const int n   = c >> 5;                   // row n (0..255)
    const int off = (c & 31) << 4;            // byte offset within 512B row
    *reinterpret_cast<f32x4*>(qb + (n << 9) + (off ^ ((n & 15) << 5))) = sv[it];
  }
  __syncthreads();

  f32x4 acc[16];
#pragma unroll
  for (int i = 0; i < 16; ++i) acc[i] = (f32x4){0.f, 0.f, 0.f, 0.f};

#pragma unroll
  for (int s = 0; s < NSTEP; ++s){
    // consume ring slot s%3: convert + 16 ds_read + 16 MFMA (full N)
    {
      const f32x4 lo = f[s % 3][0], hi = f[s % 3][1];
      short8 a;
      a[0] = (short)f2bf(lo[0]); a[1] = (short)f2bf(lo[1]);
      a[2] = (short)f2bf(lo[2]); a[3] = (short)f2bf(lo[3]);
      a[4] = (short)f2bf(hi[0]); a[5] = (short)f2bf(hi[1]);
      a[6] = (short)f2bf(hi[2]); a[7] = (short)f2bf(hi[3]);
      const int kb = (s & 7) * 64 + (lg << 4);
#pragma unroll
      for (int nt = 0; nt < 16; ++nt){
        const int n = nt * 16 + lm;
        const short8 b = *reinterpret_cast<const short8*>(
            qb + (n << 9) + (kb ^ ((n & 15) << 5)));
        acc[nt] = __builtin_amdgcn_mfma_f32_16x16x32_bf16(a, b, acc[nt], 0, 0, 0);
      }
    }
    // refill freed slot with step s+3 (crosses the generation boundary)
    if (s + 3 < NSTEP) LDX(s % 3, s + 3);
    // generation epilogue: store 16x256 strip, reset acc
    if ((s & 7) == 7){
      const size_t orow = rowbase + (size_t)(s >> 3) * 256 + wv * 16 + lg * 4;
#pragma unroll
      for (int nt = 0; nt < 16; ++nt){
#pragma unroll
        for (int r = 0; r < 4; ++r){
          Y[(orow + r) * DDIM + nt * 16 + lm] = acc[nt][r];
        }
        acc[nt] = (f32x4){0.f, 0.f, 0.f, 0.f};
      }
    }
  }
#undef LDX
}

extern "C" void kernel_launch(void* const* d_in, const int* in_sizes, int n_in,
                              void* d_out, int out_size, void* d_ws, size_t ws_size,
                              hipStream_t stream) {
  const float* X = (const float*)d_in[0];     // [131072, 256]
  const float* U = (const float*)d_in[1];     // [256, 256]
  float* Y = (float*)d_out;                   // [131072, 256]
  unsigned short* Qt = (unsigned short*)d_ws; // 256*256 bf16 = 128 KB scratch

  compute_q<<<32, 256, 0, stream>>>(U, Qt);
  gemm_xq<<<GBLK, 1024, 0, stream>>>(X, Qt, Y);
}

// Round 19
// 151.990 us; speedup vs baseline: 1.2929x; 1.2929x over previous
//
#include <hip/hip_runtime.h>
#include <hip/hip_bf16.h>

typedef __attribute__((ext_vector_type(8))) short short8;
typedef __attribute__((ext_vector_type(4))) float f32x4;

#define DDIM 256
#define NROWS 131072
#define ROWS_PER_BLK 128      // 8 waves x 16 rows
#define GBLK ((NROWS / ROWS_PER_BLK) * 4)   // 1024 rowgroups x 4 col-quarters

static __device__ __forceinline__ unsigned short f2bf(float f){
  unsigned b = __builtin_bit_cast(unsigned, f);
  b += 0x7FFFu + ((b >> 16) & 1u);          // RNE round to bf16
  return (unsigned short)(b >> 16);
}

// Wave64 sum-reduction via DPP (VALU-only). row_shr 1/2/4/8 +
// row_bcast:15/31 -> total in lane 63; readlane broadcasts.
static __device__ __forceinline__ float wave_sum_bcast(float x){
  int v = __builtin_bit_cast(int, x);
#define DPP_ADD(ctrl)                                                          \
  v = __builtin_bit_cast(int,                                                  \
        __builtin_bit_cast(float, v) +                                         \
        __builtin_bit_cast(float,                                              \
          __builtin_amdgcn_update_dpp(0, v, (ctrl), 0xF, 0xF, true)))
  DPP_ADD(0x111); DPP_ADD(0x112); DPP_ADD(0x114); DPP_ADD(0x118);
  DPP_ADD(0x142); DPP_ADD(0x143);
#undef DPP_ADD
  return __builtin_bit_cast(float, __builtin_amdgcn_readlane(v, 63));
}

// ---------------------------------------------------------------------------
// Kernel A (unchanged, verified r9-r14): Q columns via 256 Householder steps;
// 2 cols/wave, depth-4 rotating U-row prefetch, v.v inline via 3rd DPP chain.
// ---------------------------------------------------------------------------
__global__ __launch_bounds__(256) void compute_q(const float* __restrict__ U,
                                                 unsigned short* __restrict__ Qt){
  const int lane = threadIdx.x & 63;
  const int wv   = threadIdx.x >> 6;
  const int pair = blockIdx.x * 4 + wv;
  const int j0 = pair * 2, j1 = j0 + 1;

  float u0[4], u1[4], r0[4], r1[4], r2[4], r3[4];
#pragma unroll
  for (int e = 0; e < 4; ++e){
    const int i = e * 64 + lane;
    u0[e] = (i == j0) ? 1.f : 0.f;
    u1[e] = (i == j1) ? 1.f : 0.f;
    r0[e] = U[0 * 256 + i];
    r1[e] = U[1 * 256 + i];
    r2[e] = U[2 * 256 + i];
    r3[e] = U[3 * 256 + i];
  }

#define QSTEP(R, KN)                                                           \
  do {                                                                         \
    const float p0_ = (u0[0]*R[0] + u0[1]*R[1]) + (u0[2]*R[2] + u0[3]*R[3]);   \
    const float p1_ = (u1[0]*R[0] + u1[1]*R[1]) + (u1[2]*R[2] + u1[3]*R[3]);   \
    const float pv_ = (R[0]*R[0] + R[1]*R[1]) + (R[2]*R[2] + R[3]*R[3]);       \
    const float d0_ = wave_sum_bcast(p0_);                                     \
    const float d1_ = wave_sum_bcast(p1_);                                     \
    const float dv_ = wave_sum_bcast(pv_);                                     \
    const float inv_ = 2.0f * __builtin_amdgcn_rcpf(dv_);                      \
    const float c0_ = d0_ * inv_, c1_ = d1_ * inv_;                            \
    _Pragma("unroll")                                                          \
    for (int e = 0; e < 4; ++e){                                               \
      u0[e] = fmaf(-c0_, R[e], u0[e]);                                         \
      u1[e] = fmaf(-c1_, R[e], u1[e]);                                         \
      R[e] = U[(size_t)(KN) * 256 + e * 64 + lane];                            \
    }                                                                          \
  } while (0)

  for (int k = 0; k < 256; k += 4){
    const int k4 = (k+4) & 255, k5 = (k+5) & 255, k6 = (k+6) & 255, k7 = (k+7) & 255;
    QSTEP(r0, k4); QSTEP(r1, k5); QSTEP(r2, k6); QSTEP(r3, k7);
  }
#undef QSTEP

#pragma unroll
  for (int e = 0; e < 4; ++e){
    const int i = e * 64 + lane;
    Qt[(size_t)j0 * 256 + i] = f2bf(u0[e]);
    Qt[(size_t)j1 * 256 + i] = f2bf(u1[e]);
  }
}

// ---------------------------------------------------------------------------
// Kernel B: Y = X * Q, quarter-N high-occupancy.  4096 blocks x 512 thr:
// bid = rowgroup*4 + quarter; block = 128 rows x 64 cols.  Qt-quarter
// (32 KB LDS) + ~80 unified regs (xv 2x32 arch + acc[4]=16 AGPR) with
// __launch_bounds__(512,6) (85-reg cap) -> ~28 waves/CU (vs r5's 16):
// 4+ co-resident blocks whose load/compute phases interleave naturally.
// 4 consecutive bids = same 128 rows -> X re-read (x4) is L2/L3-served
// (X = 134 MB < 256 MB L3; pairing pattern verified r7: FETCH = 1x X).
// Split X bursts: b0 (kk0-3) issued before the barrier, b1 (kk4-7) issued
// before consuming b0 -> b1's HBM latency hides under b0's compute.
// Full-row XOR swizzle ((nl&15)<<5): B-read slot = (kk*4+lg)^(lm<<1) -> 2
// lanes/16B slot = conflict-free (verified r5/r7: SQ_LDS_BANK_CONFLICT=0).
// mfma_f32_16x16x32_bf16 layouts (m89/m97):
//   A: lane holds A[l&15][kk*32+8*(l>>4)+j]   B: same, n=l&15
//   D: D[(l>>4)*4+r][l&15]
// ---------------------------------------------------------------------------
__global__ __launch_bounds__(512, 6) void gemm_xq(const float* __restrict__ X,
                                                  const unsigned short* __restrict__ Qt,
                                                  float* __restrict__ Y){
  __shared__ char qb[32768];                  // 64 rows (nl) x 512 B (k, bf16)

  const int tid  = threadIdx.x;
  const int lane = tid & 63;
  const int wv   = tid >> 6;                  // 0..7
  const int lg   = lane >> 4;                 // 0..3
  const int lm   = lane & 15;
  const int quarter = blockIdx.x & 3;
  const size_t rowbase = (size_t)(blockIdx.x >> 2) * ROWS_PER_BLK;

  // --- Qt-quarter stage loads (4 x 16B per thread, from L2) ---
  f32x4 sv[4];
#pragma unroll
  for (int it = 0; it < 4; ++it){
    const int c = tid + it * 512;             // 0..2047 chunks of 16B
    sv[it] = *reinterpret_cast<const f32x4*>(
        reinterpret_cast<const char*>(Qt) +
        ((size_t)(quarter * 64) << 9) + ((size_t)c << 4));
  }

  // --- X burst 0 (kk 0..3): 8 x 16B per thread ---
  const float* xp = X + (rowbase + wv * 16 + lm) * DDIM + lg * 8;
  f32x4 xv0[8];
#pragma unroll
  for (int kk = 0; kk < 4; ++kk){
    xv0[2*kk]   = *reinterpret_cast<const f32x4*>(xp + kk * 32);
    xv0[2*kk+1] = *reinterpret_cast<const f32x4*>(xp + kk * 32 + 4);
  }

  // --- LDS writes (swizzled) + barrier (drains vmcnt once; b0 mostly
  //     landed by then anyway) ---
#pragma unroll
  for (int it = 0; it < 4; ++it){
    const int c   = tid + it * 512;
    const int n   = c >> 5;                   // local row nl (0..63)
    const int off = (c & 31) << 4;            // byte offset within 512B row
    *reinterpret_cast<f32x4*>(qb + (n << 9) + (off ^ ((n & 15) << 5))) = sv[it];
  }
  __syncthreads();

  // --- X burst 1 (kk 4..7) issued BEFORE consuming burst 0 ---
  f32x4 xv1[8];
#pragma unroll
  for (int kk = 0; kk < 4; ++kk){
    xv1[2*kk]   = *reinterpret_cast<const f32x4*>(xp + (kk + 4) * 32);
    xv1[2*kk+1] = *reinterpret_cast<const f32x4*>(xp + (kk + 4) * 32 + 4);
  }

  f32x4 acc[4];
#pragma unroll
  for (int nt = 0; nt < 4; ++nt) acc[nt] = (f32x4){0.f, 0.f, 0.f, 0.f};

#define CONSUME(XV, kkbase)                                                    \
  do {                                                                         \
    _Pragma("unroll")                                                          \
    for (int kk = 0; kk < 4; ++kk){                                            \
      const f32x4 lo = XV[2*kk], hi = XV[2*kk+1];                              \
      short8 a;                                                                \
      a[0] = (short)f2bf(lo[0]); a[1] = (short)f2bf(lo[1]);                    \
      a[2] = (short)f2bf(lo[2]); a[3] = (short)f2bf(lo[3]);                    \
      a[4] = (short)f2bf(hi[0]); a[5] = (short)f2bf(hi[1]);                    \
      a[6] = (short)f2bf(hi[2]); a[7] = (short)f2bf(hi[3]);                    \
      const int kb = (kkbase + kk) * 64 + (lg << 4);                           \
      _Pragma("unroll")                                                        \
      for (int nt = 0; nt < 4; ++nt){                                          \
        const int nl = nt * 16 + lm;                                           \
        const short8 b = *reinterpret_cast<const short8*>(                     \
            qb + (nl << 9) + (kb ^ ((nl & 15) << 5)));                         \
        acc[nt] = __builtin_amdgcn_mfma_f32_16x16x32_bf16(a, b, acc[nt],       \
                                                          0, 0, 0);            \
      }                                                                        \
    }                                                                          \
  } while (0)

  CONSUME(xv0, 0);
  CONSUME(xv1, 4);
#undef CONSUME

  // Epilogue: D[(l>>4)*4+r][l&15] per 16x16 tile.
  const size_t orow = rowbase + wv * 16 + lg * 4;
  const int col0 = quarter * 64;
#pragma unroll
  for (int nt = 0; nt < 4; ++nt){
#pragma unroll
    for (int r = 0; r < 4; ++r){
      Y[(orow + r) * DDIM + col0 + nt * 16 + lm] = acc[nt][r];
    }
  }
}

extern "C" void kernel_launch(void* const* d_in, const int* in_sizes, int n_in,
                              void* d_out, int out_size, void* d_ws, size_t ws_size,
                              hipStream_t stream) {
  const float* X = (const float*)d_in[0];     // [131072, 256]
  const float* U = (const float*)d_in[1];     // [256, 256]
  float* Y = (float*)d_out;                   // [131072, 256]
  unsigned short* Qt = (unsigned short*)d_ws; // 256*256 bf16 = 128 KB scratch

  compute_q<<<32, 256, 0, stream>>>(U, Qt);
  gemm_xq<<<GBLK, 512, 0, stream>>>(X, Qt, Y);
}

// Round 20
// 130.186 us; speedup vs baseline: 1.5095x; 1.1675x over previous
//
#include <hip/hip_runtime.h>
#include <hip/hip_bf16.h>

typedef __attribute__((ext_vector_type(8))) short short8;
typedef __attribute__((ext_vector_type(4))) float f32x4;

#define DDIM 256
#define NROWS 131072
#define ROWS_PER_BLK 128      // 8 waves x 16 rows
#define GBLK ((NROWS / ROWS_PER_BLK) * 4)   // 1024 rowgroups x 4 col-quarters

static __device__ __forceinline__ unsigned short f2bf(float f){
  unsigned b = __builtin_bit_cast(unsigned, f);
  b += 0x7FFFu + ((b >> 16) & 1u);          // RNE round to bf16
  return (unsigned short)(b >> 16);
}

// Wave64 sum-reduction via DPP (VALU-only). row_shr 1/2/4/8 +
// row_bcast:15/31 -> total in lane 63; readlane broadcasts.
static __device__ __forceinline__ float wave_sum_bcast(float x){
  int v = __builtin_bit_cast(int, x);
#define DPP_ADD(ctrl)                                                          \
  v = __builtin_bit_cast(int,                                                  \
        __builtin_bit_cast(float, v) +                                         \
        __builtin_bit_cast(float,                                              \
          __builtin_amdgcn_update_dpp(0, v, (ctrl), 0xF, 0xF, true)))
  DPP_ADD(0x111); DPP_ADD(0x112); DPP_ADD(0x114); DPP_ADD(0x118);
  DPP_ADD(0x142); DPP_ADD(0x143);
#undef DPP_ADD
  return __builtin_bit_cast(float, __builtin_amdgcn_readlane(v, 63));
}

// ---------------------------------------------------------------------------
// Kernel A (unchanged, verified r9-r19): Q columns via 256 Householder steps;
// 2 cols/wave, depth-4 rotating U-row prefetch, v.v inline via 3rd DPP chain.
// ---------------------------------------------------------------------------
__global__ __launch_bounds__(256) void compute_q(const float* __restrict__ U,
                                                 unsigned short* __restrict__ Qt){
  const int lane = threadIdx.x & 63;
  const int wv   = threadIdx.x >> 6;
  const int pair = blockIdx.x * 4 + wv;
  const int j0 = pair * 2, j1 = j0 + 1;

  float u0[4], u1[4], r0[4], r1[4], r2[4], r3[4];
#pragma unroll
  for (int e = 0; e < 4; ++e){
    const int i = e * 64 + lane;
    u0[e] = (i == j0) ? 1.f : 0.f;
    u1[e] = (i == j1) ? 1.f : 0.f;
    r0[e] = U[0 * 256 + i];
    r1[e] = U[1 * 256 + i];
    r2[e] = U[2 * 256 + i];
    r3[e] = U[3 * 256 + i];
  }

#define QSTEP(R, KN)                                                           \
  do {                                                                         \
    const float p0_ = (u0[0]*R[0] + u0[1]*R[1]) + (u0[2]*R[2] + u0[3]*R[3]);   \
    const float p1_ = (u1[0]*R[0] + u1[1]*R[1]) + (u1[2]*R[2] + u1[3]*R[3]);   \
    const float pv_ = (R[0]*R[0] + R[1]*R[1]) + (R[2]*R[2] + R[3]*R[3]);       \
    const float d0_ = wave_sum_bcast(p0_);                                     \
    const float d1_ = wave_sum_bcast(p1_);                                     \
    const float dv_ = wave_sum_bcast(pv_);                                     \
    const float inv_ = 2.0f * __builtin_amdgcn_rcpf(dv_);                      \
    const float c0_ = d0_ * inv_, c1_ = d1_ * inv_;                            \
    _Pragma("unroll")                                                          \
    for (int e = 0; e < 4; ++e){                                               \
      u0[e] = fmaf(-c0_, R[e], u0[e]);                                         \
      u1[e] = fmaf(-c1_, R[e], u1[e]);                                         \
      R[e] = U[(size_t)(KN) * 256 + e * 64 + lane];                            \
    }                                                                          \
  } while (0)

  for (int k = 0; k < 256; k += 4){
    const int k4 = (k+4) & 255, k5 = (k+5) & 255, k6 = (k+6) & 255, k7 = (k+7) & 255;
    QSTEP(r0, k4); QSTEP(r1, k5); QSTEP(r2, k6); QSTEP(r3, k7);
  }
#undef QSTEP

#pragma unroll
  for (int e = 0; e < 4; ++e){
    const int i = e * 64 + lane;
    Qt[(size_t)j0 * 256 + i] = f2bf(u0[e]);
    Qt[(size_t)j1 * 256 + i] = f2bf(u1[e]);
  }
}

// ---------------------------------------------------------------------------
// Kernel B: Y = X * Q, quarter-N high-occupancy + XCD-pairing swizzle.
// r19 measured: occupancy 77%, HBM 3.73 TB/s, BUT FETCH = 2x X because the
// 4 col-quarters of a rowgroup (consecutive bids) land on DIFFERENT XCDs ->
// no L2 sharing, L3 absorbed only half the x4 logical X re-read.
// Fix (single change): physical bid p -> quarter=(p>>3)&3, rg=(p>>5)*8+(p&7).
// All 4 carriers of a rowgroup share p&7 -> same XCD (round-robin dispatch),
// ~8-24 slots apart -> concurrent; X rows (128 KB) + Qt quarter (32 KB) stay
// in that XCD's 4 MB L2 -> HBM reads X once.  Predicted FETCH 262 -> ~140 MB.
// Block = 128 rows x 64 cols, 8 waves; 32 KB LDS; ~48 unified regs ->
// 4 blocks/CU resident (wave cap).  Split X bursts hide b1 under b0 compute.
// Full-row XOR swizzle ((nl&15)<<5) conflict-free (r5/r7/r19: 0).
// mfma_f32_16x16x32_bf16 layouts (m89/m97):
//   A: lane holds A[l&15][kk*32+8*(l>>4)+j]   B: same, n=l&15
//   D: D[(l>>4)*4+r][l&15]
// ---------------------------------------------------------------------------
__global__ __launch_bounds__(512, 6) void gemm_xq(const float* __restrict__ X,
                                                  const unsigned short* __restrict__ Qt,
                                                  float* __restrict__ Y){
  __shared__ char qb[32768];                  // 64 rows (nl) x 512 B (k, bf16)

  const int tid  = threadIdx.x;
  const int lane = tid & 63;
  const int wv   = tid >> 6;                  // 0..7
  const int lg   = lane >> 4;                 // 0..3
  const int lm   = lane & 15;

  // XCD-pairing decomposition (see header comment).
  const int p = blockIdx.x;
  const int quarter = (p >> 3) & 3;
  const size_t rowbase = ((size_t)(p >> 5) * 8 + (p & 7)) * ROWS_PER_BLK;

  // --- Qt-quarter stage loads (4 x 16B per thread, from L2) ---
  f32x4 sv[4];
#pragma unroll
  for (int it = 0; it < 4; ++it){
    const int c = tid + it * 512;             // 0..2047 chunks of 16B
    sv[it] = *reinterpret_cast<const f32x4*>(
        reinterpret_cast<const char*>(Qt) +
        ((size_t)(quarter * 64) << 9) + ((size_t)c << 4));
  }

  // --- X burst 0 (kk 0..3): 8 x 16B per thread ---
  const float* xp = X + (rowbase + wv * 16 + lm) * DDIM + lg * 8;
  f32x4 xv0[8];
#pragma unroll
  for (int kk = 0; kk < 4; ++kk){
    xv0[2*kk]   = *reinterpret_cast<const f32x4*>(xp + kk * 32);
    xv0[2*kk+1] = *reinterpret_cast<const f32x4*>(xp + kk * 32 + 4);
  }

  // --- LDS writes (swizzled) + barrier ---
#pragma unroll
  for (int it = 0; it < 4; ++it){
    const int c   = tid + it * 512;
    const int n   = c >> 5;                   // local row nl (0..63)
    const int off = (c & 31) << 4;            // byte offset within 512B row
    *reinterpret_cast<f32x4*>(qb + (n << 9) + (off ^ ((n & 15) << 5))) = sv[it];
  }
  __syncthreads();

  // --- X burst 1 (kk 4..7) issued BEFORE consuming burst 0 ---
  f32x4 xv1[8];
#pragma unroll
  for (int kk = 0; kk < 4; ++kk){
    xv1[2*kk]   = *reinterpret_cast<const f32x4*>(xp + (kk + 4) * 32);
    xv1[2*kk+1] = *reinterpret_cast<const f32x4*>(xp + (kk + 4) * 32 + 4);
  }

  f32x4 acc[4];
#pragma unroll
  for (int nt = 0; nt < 4; ++nt) acc[nt] = (f32x4){0.f, 0.f, 0.f, 0.f};

#define CONSUME(XV, kkbase)                                                    \
  do {                                                                         \
    _Pragma("unroll")                                                          \
    for (int kk = 0; kk < 4; ++kk){                                            \
      const f32x4 lo = XV[2*kk], hi = XV[2*kk+1];                              \
      short8 a;                                                                \
      a[0] = (short)f2bf(lo[0]); a[1] = (short)f2bf(lo[1]);                    \
      a[2] = (short)f2bf(lo[2]); a[3] = (short)f2bf(lo[3]);                    \
      a[4] = (short)f2bf(hi[0]); a[5] = (short)f2bf(hi[1]);                    \
      a[6] = (short)f2bf(hi[2]); a[7] = (short)f2bf(hi[3]);                    \
      const int kb = (kkbase + kk) * 64 + (lg << 4);                           \
      _Pragma("unroll")                                                        \
      for (int nt = 0; nt < 4; ++nt){                                          \
        const int nl = nt * 16 + lm;                                           \
        const short8 b = *reinterpret_cast<const short8*>(                     \
            qb + (nl << 9) + (kb ^ ((nl & 15) << 5)));                         \
        acc[nt] = __builtin_amdgcn_mfma_f32_16x16x32_bf16(a, b, acc[nt],       \
                                                          0, 0, 0);            \
      }                                                                        \
    }                                                                          \
  } while (0)

  CONSUME(xv0, 0);
  CONSUME(xv1, 4);
#undef CONSUME

  // Epilogue: D[(l>>4)*4+r][l&15] per 16x16 tile.
  const size_t orow = rowbase + wv * 16 + lg * 4;
  const int col0 = quarter * 64;
#pragma unroll
  for (int nt = 0; nt < 4; ++nt){
#pragma unroll
    for (int r = 0; r < 4; ++r){
      Y[(orow + r) * DDIM + col0 + nt * 16 + lm] = acc[nt][r];
    }
  }
}

extern "C" void kernel_launch(void* const* d_in, const int* in_sizes, int n_in,
                              void* d_out, int out_size, void* d_ws, size_t ws_size,
                              hipStream_t stream) {
  const float* X = (const float*)d_in[0];     // [131072, 256]
  const float* U = (const float*)d_in[1];     // [256, 256]
  float* Y = (float*)d_out;                   // [131072, 256]
  unsigned short* Qt = (unsigned short*)d_ws; // 256*256 bf16 = 128 KB scratch

  compute_q<<<32, 256, 0, stream>>>(U, Qt);
  gemm_xq<<<GBLK, 512, 0, stream>>>(X, Qt, Y);
}